// Round 17
// baseline (87.231 us; speedup 1.0000x reference)
//
#include <hip/hip_runtime.h>
#include <hip/hip_fp16.h>

#define NNODES 50000
#define NEDGES 640000
#define NF 128
#define XB 3125           // xh conversion blocks: 3125*256*8 = 50000*128
#define BINS 196          // coarse bins by dst>>8
#define BINCAP 4096       // per-bin capacity (mean 3265, +14 sigma)
#define P1AB 313          // sort blocks: 313*2048 >= 640000
#define EPB 2048          // edges per sort block

typedef __attribute__((ext_vector_type(8))) _Float16 f16x8;
typedef __attribute__((ext_vector_type(4))) float f32x4;

// ---------------- K: fused prep — xh convert | p1a per-block bin counts ----------------
__global__ __launch_bounds__(256) void k_prep(const float* __restrict__ x,
                                              const int* __restrict__ ei,
                                              unsigned short* __restrict__ xh,
                                              int* __restrict__ cnt,
                                              float* __restrict__ stats) {
  __shared__ int lcnt[BINS];
  const int bid = blockIdx.x, t = threadIdx.x;
  if (bid < XB) {
    int i = bid * 256 + t;     // 8-float chunk index
    const float4 a = ((const float4*)x)[2 * i];
    const float4 b = ((const float4*)x)[2 * i + 1];
    __half2 h0 = __float22half2_rn(make_float2(a.x, a.y));
    __half2 h1 = __float22half2_rn(make_float2(a.z, a.w));
    __half2 h2 = __float22half2_rn(make_float2(b.x, b.y));
    __half2 h3 = __float22half2_rn(make_float2(b.z, b.w));
    uint4 v;
    v.x = *(unsigned*)&h0; v.y = *(unsigned*)&h1;
    v.z = *(unsigned*)&h2; v.w = *(unsigned*)&h3;
    ((uint4*)xh)[i] = v;
    if (bid == 0) { stats[t] = 0.f; stats[256 + t] = 0.f; }
  } else {
    // ---- p1a: per-block histogram of dst>>8 (LDS atomics only) ----
    const int blk = bid - XB;
    const int e0 = blk * EPB;
    const bool full = (e0 + EPB <= NEDGES);
    if (t < BINS) lcnt[t] = 0;
    __syncthreads();
    const int4 d0 = *(const int4*)(ei + NEDGES + e0 + 4 * t);
    atomicAdd(&lcnt[d0.x >> 8], 1);
    atomicAdd(&lcnt[d0.y >> 8], 1);
    atomicAdd(&lcnt[d0.z >> 8], 1);
    atomicAdd(&lcnt[d0.w >> 8], 1);
    if (full) {
      const int4 d1 = *(const int4*)(ei + NEDGES + e0 + 1024 + 4 * t);
      atomicAdd(&lcnt[d1.x >> 8], 1);
      atomicAdd(&lcnt[d1.y >> 8], 1);
      atomicAdd(&lcnt[d1.z >> 8], 1);
      atomicAdd(&lcnt[d1.w >> 8], 1);
    }
    __syncthreads();
    if (t < BINS) cnt[blk * BINS + t] = lcnt[t];
  }
}

// ---------------- K: p1b — per-bin scan over blocks: base[blk][bin], gtot[bin] ---------
__global__ __launch_bounds__(512) void k_p1b(const int* __restrict__ cnt,
                                             int* __restrict__ base,
                                             int* __restrict__ gtot) {
  __shared__ int s[512];
  const int t = threadIdx.x, b = blockIdx.x;
  const int v = (t < P1AB) ? cnt[t * BINS + b] : 0;
  s[t] = v;
  __syncthreads();
  for (int d = 1; d < 512; d <<= 1) {
    int u = (t >= d) ? s[t - d] : 0;
    __syncthreads();
    s[t] += u;
    __syncthreads();
  }
  if (t < P1AB) base[t * BINS + b] = s[t] - v;
  if (t == 511) gtot[b] = s[511];
}

// ---------------- K: p1c — scatter into binbuf using deterministic bases ---------------
__global__ __launch_bounds__(256) void k_p1c(const int* __restrict__ ei,
                                             const int* __restrict__ base,
                                             unsigned* __restrict__ binbuf) {
  __shared__ int lcur[BINS];
  const int t = threadIdx.x, blk = blockIdx.x;
  const int e0 = blk * EPB;
  const bool full = (e0 + EPB <= NEDGES);
  if (t < BINS) lcur[t] = base[blk * BINS + t];
  __syncthreads();
  const int4 s0 = *(const int4*)(ei + e0 + 4 * t);
  const int4 d0 = *(const int4*)(ei + NEDGES + e0 + 4 * t);
#define SCAT(ss, dd)                                                             \
  {                                                                              \
    int bin = (dd) >> 8;                                                         \
    int pos = atomicAdd(&lcur[bin], 1);                                          \
    if (pos < BINCAP)                                                            \
      binbuf[bin * BINCAP + pos] = ((unsigned)((dd) & 255) << 16) | (unsigned)(ss); \
  }
  SCAT(s0.x, d0.x); SCAT(s0.y, d0.y); SCAT(s0.z, d0.z); SCAT(s0.w, d0.w);
  if (full) {
    const int4 s1 = *(const int4*)(ei + e0 + 1024 + 4 * t);
    const int4 d1 = *(const int4*)(ei + NEDGES + e0 + 1024 + 4 * t);
    SCAT(s1.x, d1.x); SCAT(s1.y, d1.y); SCAT(s1.z, d1.z); SCAT(s1.w, d1.w);
  }
#undef SCAT
}

// ---------------- K: phase 2 — per-bin exact sort; CSR begdeg + ushort slot ------------
__global__ __launch_bounds__(256) void k_p2(const unsigned* __restrict__ binbuf,
                                            const int* __restrict__ gtot,
                                            int* __restrict__ begdeg,
                                            unsigned short* __restrict__ slot) {
  __shared__ int cnt2[256], pst[256];
  __shared__ unsigned short stg[BINCAP];
  const int t = threadIdx.x;
  const int b = blockIdx.x;
  const int base = b * BINCAP;
  const int nb = min(gtot[b], BINCAP);
  unsigned pk[16];
#pragma unroll
  for (int ci = 0; ci < 16; ++ci) {
    int i = (ci << 8) + t;
    pk[ci] = (i < nb) ? binbuf[base + i] : 0xFFFFFFFFu;
  }
  cnt2[t] = 0;
  __syncthreads();
#pragma unroll
  for (int ci = 0; ci < 16; ++ci)
    if (pk[ci] != 0xFFFFFFFFu) atomicAdd(&cnt2[(int)(pk[ci] >> 16)], 1);
  __syncthreads();
  pst[t] = cnt2[t];
  __syncthreads();
  for (int d = 1; d < 256; d <<= 1) {
    int u = (t >= d) ? pst[t - d] : 0;
    __syncthreads();
    pst[t] += u;
    __syncthreads();
  }
  pst[t] -= cnt2[t];   // exclusive prefix
  int node = (b << 8) + t;
  if (node < NNODES)
    begdeg[node] = ((base + pst[t]) << 8) | min(cnt2[t], 255);
  cnt2[t] = 0;
  __syncthreads();
#pragma unroll
  for (int ci = 0; ci < 16; ++ci)
    if (pk[ci] != 0xFFFFFFFFu) {
      int dl = (int)(pk[ci] >> 16);
      int pos = atomicAdd(&cnt2[dl], 1);
      stg[pst[dl] + pos] = (unsigned short)(pk[ci] & 0xffffu);
    }
  __syncthreads();
  for (int i = t; i < nb; i += 256) slot[base + i] = stg[i];
}

// ---------------- K: gather-sum, 4-deep MLP (16 edges in flight per wave) --------------
__device__ inline void add8h(float* a, uint4 v) {
  const __half2* p = (const __half2*)&v;
#pragma unroll
  for (int q = 0; q < 4; ++q) {
    float2 f = __half22float2(p[q]);
    a[2 * q] += f.x;
    a[2 * q + 1] += f.y;
  }
}

__global__ __launch_bounds__(256) void k_gather(const unsigned short* __restrict__ xh,
                                                const int* __restrict__ begdeg,
                                                const unsigned short* __restrict__ slot,
                                                _Float16* __restrict__ h) {
  const int t = threadIdx.x;
  const int wv = t >> 6, l = t & 63;
  const int node = blockIdx.x * 4 + wv;
  if (node >= NNODES) return;
  const int cg_ = (l & 15) << 3;   // half-index base (16B per lane, 16 lanes = 256B row)
  const int e = l >> 4;            // 0..3 edge-slots in parallel
  const int bd = begdeg[node];
  const int beg = bd >> 8;
  const int end = beg + (bd & 255);
  float a[8] = {0.f, 0.f, 0.f, 0.f, 0.f, 0.f, 0.f, 0.f};
  // 4 independent guarded row-loads per lane per iteration -> 16 edges in flight/wave
  for (int j = beg + e; j < end; j += 16) {
    const bool g1 = j + 4 < end, g2 = j + 8 < end, g3 = j + 12 < end;
    uint4 v0, v1, v2, v3;
    v0 = *(const uint4*)(xh + (size_t)slot[j] * NF + cg_);
    if (g1) v1 = *(const uint4*)(xh + (size_t)slot[j + 4] * NF + cg_);
    if (g2) v2 = *(const uint4*)(xh + (size_t)slot[j + 8] * NF + cg_);
    if (g3) v3 = *(const uint4*)(xh + (size_t)slot[j + 12] * NF + cg_);
    add8h(a, v0);
    if (g1) add8h(a, v1);
    if (g2) add8h(a, v2);
    if (g3) add8h(a, v3);
  }
#pragma unroll
  for (int q = 0; q < 8; ++q) {
    a[q] += __shfl_xor(a[q], 16);
    a[q] += __shfl_xor(a[q], 32);
  }
  if (e == 0) {
    const uint4 sv = *(const uint4*)(xh + (size_t)node * NF + cg_);  // self term
    add8h(a, sv);
    f16x8 o;
#pragma unroll
    for (int q = 0; q < 8; ++q) o[q] = (_Float16)a[q];
    *(f16x8*)(h + (size_t)node * NF + cg_) = o;
  }
}

// ---------------- MFMA GEMM, single-plane fp16 W (inline prep; BN fold MODE 1) ---------
// MODE 0: W=W1, bias=b1; relu -> fp16 h1, BN sum/sumsq atomics.
// MODE 1: W=W2 scaled by BN sc (from stats), bias=b2'=b2+sh@W2; -> fp32 d_out.
template <int MODE>
__global__ __launch_bounds__(256, 3) void k_gemm(const _Float16* __restrict__ A,
                                                 const float* __restrict__ W,
                                                 const float* __restrict__ bias,
                                                 const float* __restrict__ gamma,
                                                 const float* __restrict__ beta,
                                                 float* __restrict__ stats,
                                                 _Float16* __restrict__ outh,
                                                 float* __restrict__ outf) {
  __shared__ _Float16 wl[16384];   // 32 KB: fp16 W, frag-ordered (single plane)
  __shared__ float red[2][4][128]; // 4 KB: BN cross-wave reduce / b2' partials
  __shared__ float scs[128], shs[128], b2sh[128];

  const int t = threadIdx.x;
  const int wv = t >> 6;
  const int l = t & 63;
  const int wrow0 = blockIdx.x * 128 + wv * 16;

  // ---- A fragments first (long-latency loads overlap the W build) ----
  f16x8 areg[2][4];
#pragma unroll
  for (int m = 0; m < 2; ++m) {
    const int arow = wrow0 + m * 64 + (l & 15);
    const bool okA = arow < NNODES;
#pragma unroll
    for (int ks = 0; ks < 4; ++ks) {
      if (okA) {
        areg[m][ks] = *(const f16x8*)(A + (size_t)arow * NF + ks * 32 + ((l >> 4) << 3));
      } else {
        areg[m][ks] = (f16x8){};
      }
    }
  }

  // ---- BN scale/shift (MODE 1) ----
  if (MODE == 1) {
    if (t < 128) {
      const float inv = 1.0f / (float)NNODES;
      float mean = stats[t] * inv;
      float var = fmaxf(stats[128 + t] * inv - mean * mean, 0.f);
      float sc = gamma[t] * rsqrtf(var + 1e-5f);
      scs[t] = sc;
      shs[t] = beta[t] - mean * sc;
    }
    __syncthreads();
  }

  // ---- build frag-ordered fp16 W in LDS directly from fp32 W (single plane) ----
#pragma unroll
  for (int oct = 0; oct < 8; ++oct) {
    int f8 = oct * 256 + t;
    int ks = f8 >> 9, cf = (f8 >> 6) & 7, lane = f8 & 63;
    int k0 = ks * 32 + ((lane >> 4) << 3);
    int n = cf * 16 + (lane & 15);
    f16x8 hi;
#pragma unroll
    for (int j = 0; j < 8; ++j) {
      float w = W[(k0 + j) * NF + n];
      if (MODE == 1) w *= scs[k0 + j];
      hi[j] = (_Float16)w;
    }
    *(f16x8*)(wl + f8 * 8) = hi;
  }

  // ---- b2' = b2 + sh @ W2 (MODE 1), 2-way k-parallel ----
  if (MODE == 1) {
    const int col = t & 127, half = t >> 7;
    float s = 0.f;
    for (int k = half * 64; k < half * 64 + 64; ++k) s += shs[k] * W[k * NF + col];
    red[0][half][col] = s;
  }
  __syncthreads();
  if (MODE == 1) {
    if (t < 128) b2sh[t] = bias[t] + red[0][0][t] + red[0][1][t];
    __syncthreads();
  }

  // ---- compute: 1 MFMA per (m,cf,ks) ----
  f32x4 acc[2][8];
#pragma unroll
  for (int m = 0; m < 2; ++m)
#pragma unroll
    for (int cf = 0; cf < 8; ++cf) acc[m][cf] = (f32x4){0.f, 0.f, 0.f, 0.f};

#pragma unroll
  for (int ks = 0; ks < 4; ++ks) {
#pragma unroll
    for (int cf = 0; cf < 8; ++cf) {
      const int fo = (((ks * 8 + cf) << 6) + l) << 3;   // half-elem offset
      f16x8 bh = *(const f16x8*)(wl + fo);
#pragma unroll
      for (int m = 0; m < 2; ++m) {
        acc[m][cf] = __builtin_amdgcn_mfma_f32_16x16x32_f16(areg[m][ks], bh, acc[m][cf], 0, 0, 0);
      }
    }
  }

  // ---- epilogue: D layout col = cf*16+(l&15), row = wrow0 + m*64 + (l>>4)*4 + r ----
  const int col16 = l & 15;
  const int rg = l >> 4;
  float bl_[8];
#pragma unroll
  for (int cf = 0; cf < 8; ++cf)
    bl_[cf] = (MODE == 0) ? bias[cf * 16 + col16] : b2sh[cf * 16 + col16];

  if (MODE == 0) {
    float cs[8], cq[8];
#pragma unroll
    for (int cf = 0; cf < 8; ++cf) { cs[cf] = 0.f; cq[cf] = 0.f; }
#pragma unroll
    for (int m = 0; m < 2; ++m)
#pragma unroll
      for (int cf = 0; cf < 8; ++cf) {
#pragma unroll
        for (int r = 0; r < 4; ++r) {
          int row = wrow0 + m * 64 + rg * 4 + r;
          if (row < NNODES) {
            float v = fmaxf(acc[m][cf][r] + bl_[cf], 0.f);
            outh[(size_t)row * NF + cf * 16 + col16] = (_Float16)v;
            cs[cf] += v;
            cq[cf] += v * v;
          }
        }
      }
#pragma unroll
    for (int cf = 0; cf < 8; ++cf) {
      cs[cf] += __shfl_xor(cs[cf], 16); cs[cf] += __shfl_xor(cs[cf], 32);
      cq[cf] += __shfl_xor(cq[cf], 16); cq[cf] += __shfl_xor(cq[cf], 32);
    }
    __syncthreads();
    if (l < 16) {
#pragma unroll
      for (int cf = 0; cf < 8; ++cf) {
        red[0][wv][cf * 16 + l] = cs[cf];
        red[1][wv][cf * 16 + l] = cq[cf];
      }
    }
    __syncthreads();
    if (t < 128) {
      float s = red[0][0][t] + red[0][1][t] + red[0][2][t] + red[0][3][t];
      float q = red[1][0][t] + red[1][1][t] + red[1][2][t] + red[1][3][t];
      unsafeAtomicAdd(stats + t, s);
      unsafeAtomicAdd(stats + 128 + t, q);
    }
  } else {
#pragma unroll
    for (int m = 0; m < 2; ++m)
#pragma unroll
      for (int cf = 0; cf < 8; ++cf) {
#pragma unroll
        for (int r = 0; r < 4; ++r) {
          int row = wrow0 + m * 64 + rg * 4 + r;
          if (row < NNODES)
            outf[(size_t)row * NF + cf * 16 + col16] = acc[m][cf][r] + bl_[cf];
        }
      }
  }
}

extern "C" void kernel_launch(void* const* d_in, const int* in_sizes, int n_in,
                              void* d_out, int out_size, void* d_ws, size_t ws_size,
                              hipStream_t stream) {
  const float* x     = (const float*)d_in[0];
  const int*   ei    = (const int*)d_in[1];
  const float* W1    = (const float*)d_in[2];
  const float* b1    = (const float*)d_in[3];
  const float* gamma = (const float*)d_in[4];
  const float* beta  = (const float*)d_in[5];
  const float* W2    = (const float*)d_in[6];
  const float* b2    = (const float*)d_in[7];
  float* out = (float*)d_out;

  // h (gather output, fp16) lives in d_out — fully consumed by GEMM1 before GEMM2
  // overwrites d_out with the final fp32 result.
  _Float16* h = (_Float16*)d_out;

  // workspace layout (~31 MB); 16B alignment maintained
  float*          stats  = (float*)d_ws;                        // [512]
  int*            cnt    = (int*)(stats + 512);                 // [P1AB*BINS] pad 61376
  int*            basep  = cnt + 61376;                         // [P1AB*BINS] pad 61376
  int*            gtot   = basep + 61376;                       // [256]
  int*            begdeg = gtot + 256;                          // [50176]
  unsigned*       binbuf = (unsigned*)(begdeg + 50176);         // [BINS*BINCAP] 3.2 MB
  unsigned short* slot   = (unsigned short*)(binbuf + BINS * BINCAP); // 1.6 MB
  unsigned short* xh     = slot + BINS * BINCAP;                // [NNODES*NF] fp16 12.8 MB
  _Float16*       h1     = (_Float16*)(xh + (size_t)NNODES * NF);     // 12.8 MB

  k_prep   <<<XB + P1AB, 256, 0, stream>>>(x, ei, xh, cnt, stats);
  k_p1b    <<<BINS, 512, 0, stream>>>(cnt, basep, gtot);
  k_p1c    <<<P1AB, 256, 0, stream>>>(ei, basep, binbuf);
  k_p2     <<<BINS, 256, 0, stream>>>(binbuf, gtot, begdeg, slot);
  k_gather <<<(NNODES + 3) / 4, 256, 0, stream>>>(xh, begdeg, slot, h);
  k_gemm<0><<<(NNODES + 127) / 128, 256, 0, stream>>>(h, W1, b1, nullptr, nullptr,
                                                      stats, h1, nullptr);
  k_gemm<1><<<(NNODES + 127) / 128, 256, 0, stream>>>(h1, W2, b2, gamma, beta,
                                                      stats, nullptr, out);
}

// Round 18
// 86.232 us; speedup vs baseline: 1.0116x; 1.0116x over previous
//
#include <hip/hip_runtime.h>
#include <hip/hip_fp16.h>

#define NNODES 50000
#define NEDGES 640000
#define NF 128
#define XB 3125           // xh conversion blocks: 3125*256*8 = 50000*128
#define BINS 196          // coarse bins by dst>>8
#define BINCAP 4096       // per-bin capacity (mean 3265, +14 sigma)
#define P1AB 313          // sort blocks: 313*2048 >= 640000
#define EPB 2048          // edges per sort block

typedef __attribute__((ext_vector_type(8))) _Float16 f16x8;
typedef __attribute__((ext_vector_type(4))) float f32x4;

// ---------------- K: fused prep — xh convert | p1a per-block bin counts ----------------
__global__ __launch_bounds__(256) void k_prep(const float* __restrict__ x,
                                              const int* __restrict__ ei,
                                              unsigned short* __restrict__ xh,
                                              int* __restrict__ cnt,
                                              float* __restrict__ stats) {
  __shared__ int lcnt[BINS];
  const int bid = blockIdx.x, t = threadIdx.x;
  if (bid < XB) {
    int i = bid * 256 + t;     // 8-float chunk index
    const float4 a = ((const float4*)x)[2 * i];
    const float4 b = ((const float4*)x)[2 * i + 1];
    __half2 h0 = __float22half2_rn(make_float2(a.x, a.y));
    __half2 h1 = __float22half2_rn(make_float2(a.z, a.w));
    __half2 h2 = __float22half2_rn(make_float2(b.x, b.y));
    __half2 h3 = __float22half2_rn(make_float2(b.z, b.w));
    uint4 v;
    v.x = *(unsigned*)&h0; v.y = *(unsigned*)&h1;
    v.z = *(unsigned*)&h2; v.w = *(unsigned*)&h3;
    ((uint4*)xh)[i] = v;
    if (bid == 0) { stats[t] = 0.f; stats[256 + t] = 0.f; }
  } else {
    // ---- p1a: per-block histogram of dst>>8 (LDS atomics only) ----
    const int blk = bid - XB;
    const int e0 = blk * EPB;
    const bool full = (e0 + EPB <= NEDGES);
    if (t < BINS) lcnt[t] = 0;
    __syncthreads();
    const int4 d0 = *(const int4*)(ei + NEDGES + e0 + 4 * t);
    atomicAdd(&lcnt[d0.x >> 8], 1);
    atomicAdd(&lcnt[d0.y >> 8], 1);
    atomicAdd(&lcnt[d0.z >> 8], 1);
    atomicAdd(&lcnt[d0.w >> 8], 1);
    if (full) {
      const int4 d1 = *(const int4*)(ei + NEDGES + e0 + 1024 + 4 * t);
      atomicAdd(&lcnt[d1.x >> 8], 1);
      atomicAdd(&lcnt[d1.y >> 8], 1);
      atomicAdd(&lcnt[d1.z >> 8], 1);
      atomicAdd(&lcnt[d1.w >> 8], 1);
    }
    __syncthreads();
    if (t < BINS) cnt[blk * BINS + t] = lcnt[t];
  }
}

// ---------------- K: p1b — per-bin scan over blocks: base[blk][bin], gtot[bin] ---------
__global__ __launch_bounds__(512) void k_p1b(const int* __restrict__ cnt,
                                             int* __restrict__ base,
                                             int* __restrict__ gtot) {
  __shared__ int s[512];
  const int t = threadIdx.x, b = blockIdx.x;
  const int v = (t < P1AB) ? cnt[t * BINS + b] : 0;
  s[t] = v;
  __syncthreads();
  for (int d = 1; d < 512; d <<= 1) {
    int u = (t >= d) ? s[t - d] : 0;
    __syncthreads();
    s[t] += u;
    __syncthreads();
  }
  if (t < P1AB) base[t * BINS + b] = s[t] - v;
  if (t == 511) gtot[b] = s[511];
}

// ---------------- K: p1c — scatter into binbuf using deterministic bases ---------------
__global__ __launch_bounds__(256) void k_p1c(const int* __restrict__ ei,
                                             const int* __restrict__ base,
                                             unsigned* __restrict__ binbuf) {
  __shared__ int lcur[BINS];
  const int t = threadIdx.x, blk = blockIdx.x;
  const int e0 = blk * EPB;
  const bool full = (e0 + EPB <= NEDGES);
  if (t < BINS) lcur[t] = base[blk * BINS + t];
  __syncthreads();
  const int4 s0 = *(const int4*)(ei + e0 + 4 * t);
  const int4 d0 = *(const int4*)(ei + NEDGES + e0 + 4 * t);
#define SCAT(ss, dd)                                                             \
  {                                                                              \
    int bin = (dd) >> 8;                                                         \
    int pos = atomicAdd(&lcur[bin], 1);                                          \
    if (pos < BINCAP)                                                            \
      binbuf[bin * BINCAP + pos] = ((unsigned)((dd) & 255) << 16) | (unsigned)(ss); \
  }
  SCAT(s0.x, d0.x); SCAT(s0.y, d0.y); SCAT(s0.z, d0.z); SCAT(s0.w, d0.w);
  if (full) {
    const int4 s1 = *(const int4*)(ei + e0 + 1024 + 4 * t);
    const int4 d1 = *(const int4*)(ei + NEDGES + e0 + 1024 + 4 * t);
    SCAT(s1.x, d1.x); SCAT(s1.y, d1.y); SCAT(s1.z, d1.z); SCAT(s1.w, d1.w);
  }
#undef SCAT
}

// ---------------- K: phase 2 — per-bin exact sort; CSR begdeg + ushort slot ------------
__global__ __launch_bounds__(256) void k_p2(const unsigned* __restrict__ binbuf,
                                            const int* __restrict__ gtot,
                                            int* __restrict__ begdeg,
                                            unsigned short* __restrict__ slot) {
  __shared__ int cnt2[256], pst[256];
  __shared__ unsigned short stg[BINCAP];
  const int t = threadIdx.x;
  const int b = blockIdx.x;
  const int base = b * BINCAP;
  const int nb = min(gtot[b], BINCAP);
  unsigned pk[16];
#pragma unroll
  for (int ci = 0; ci < 16; ++ci) {
    int i = (ci << 8) + t;
    pk[ci] = (i < nb) ? binbuf[base + i] : 0xFFFFFFFFu;
  }
  cnt2[t] = 0;
  __syncthreads();
#pragma unroll
  for (int ci = 0; ci < 16; ++ci)
    if (pk[ci] != 0xFFFFFFFFu) atomicAdd(&cnt2[(int)(pk[ci] >> 16)], 1);
  __syncthreads();
  pst[t] = cnt2[t];
  __syncthreads();
  for (int d = 1; d < 256; d <<= 1) {
    int u = (t >= d) ? pst[t - d] : 0;
    __syncthreads();
    pst[t] += u;
    __syncthreads();
  }
  pst[t] -= cnt2[t];   // exclusive prefix
  int node = (b << 8) + t;
  if (node < NNODES)
    begdeg[node] = ((base + pst[t]) << 8) | min(cnt2[t], 255);
  cnt2[t] = 0;
  __syncthreads();
#pragma unroll
  for (int ci = 0; ci < 16; ++ci)
    if (pk[ci] != 0xFFFFFFFFu) {
      int dl = (int)(pk[ci] >> 16);
      int pos = atomicAdd(&cnt2[dl], 1);
      stg[pst[dl] + pos] = (unsigned short)(pk[ci] & 0xffffu);
    }
  __syncthreads();
  for (int i = t; i < nb; i += 256) slot[base + i] = stg[i];
}

// ---------------- K: gather-sum from fp16 table, wave per node, fp16 out ----------------
__device__ inline void add8h(float* a, uint4 v) {
  const __half2* p = (const __half2*)&v;
#pragma unroll
  for (int q = 0; q < 4; ++q) {
    float2 f = __half22float2(p[q]);
    a[2 * q] += f.x;
    a[2 * q + 1] += f.y;
  }
}

__global__ __launch_bounds__(256) void k_gather(const unsigned short* __restrict__ xh,
                                                const int* __restrict__ begdeg,
                                                const unsigned short* __restrict__ slot,
                                                _Float16* __restrict__ h) {
  const int t = threadIdx.x;
  const int wv = t >> 6, l = t & 63;
  const int node = blockIdx.x * 4 + wv;
  if (node >= NNODES) return;
  const int cg_ = (l & 15) << 3;   // half-index base (16B per lane, 16 lanes = 256B row)
  const int e = l >> 4;            // 0..3 edges in parallel
  const int bd = begdeg[node];
  const int beg = bd >> 8;
  const int end = beg + (bd & 255);
  float a[8] = {0.f, 0.f, 0.f, 0.f, 0.f, 0.f, 0.f, 0.f};
  float b[8] = {0.f, 0.f, 0.f, 0.f, 0.f, 0.f, 0.f, 0.f};
  int j = beg + e;
  for (; j + 4 < end; j += 8) {
    const uint4 v0 = *(const uint4*)(xh + (size_t)slot[j] * NF + cg_);
    const uint4 v1 = *(const uint4*)(xh + (size_t)slot[j + 4] * NF + cg_);
    add8h(a, v0);
    add8h(b, v1);
  }
  if (j < end) {
    const uint4 v0 = *(const uint4*)(xh + (size_t)slot[j] * NF + cg_);
    add8h(a, v0);
  }
#pragma unroll
  for (int q = 0; q < 8; ++q) a[q] += b[q];
#pragma unroll
  for (int q = 0; q < 8; ++q) {
    a[q] += __shfl_xor(a[q], 16);
    a[q] += __shfl_xor(a[q], 32);
  }
  if (e == 0) {
    const uint4 sv = *(const uint4*)(xh + (size_t)node * NF + cg_);  // self term
    add8h(a, sv);
    f16x8 o;
#pragma unroll
    for (int q = 0; q < 8; ++q) o[q] = (_Float16)a[q];
    *(f16x8*)(h + (size_t)node * NF + cg_) = o;
  }
}

// ---------------- MFMA GEMM, single-plane fp16 W (inline prep; BN fold MODE 1) ---------
// MODE 0: W=W1, bias=b1; relu -> fp16 h1, BN sum/sumsq atomics.
// MODE 1: W=W2 scaled by BN sc (from stats), bias=b2'=b2+sh@W2; -> fp32 d_out.
template <int MODE>
__global__ __launch_bounds__(256, 3) void k_gemm(const _Float16* __restrict__ A,
                                                 const float* __restrict__ W,
                                                 const float* __restrict__ bias,
                                                 const float* __restrict__ gamma,
                                                 const float* __restrict__ beta,
                                                 float* __restrict__ stats,
                                                 _Float16* __restrict__ outh,
                                                 float* __restrict__ outf) {
  __shared__ _Float16 wl[16384];   // 32 KB: fp16 W, frag-ordered (single plane)
  __shared__ float red[2][4][128]; // 4 KB: BN cross-wave reduce / b2' partials
  __shared__ float scs[128], shs[128], b2sh[128];

  const int t = threadIdx.x;
  const int wv = t >> 6;
  const int l = t & 63;
  const int wrow0 = blockIdx.x * 128 + wv * 16;

  // ---- A fragments first (long-latency loads overlap the W build) ----
  f16x8 areg[2][4];
#pragma unroll
  for (int m = 0; m < 2; ++m) {
    const int arow = wrow0 + m * 64 + (l & 15);
    const bool okA = arow < NNODES;
#pragma unroll
    for (int ks = 0; ks < 4; ++ks) {
      if (okA) {
        areg[m][ks] = *(const f16x8*)(A + (size_t)arow * NF + ks * 32 + ((l >> 4) << 3));
      } else {
        areg[m][ks] = (f16x8){};
      }
    }
  }

  // ---- BN scale/shift (MODE 1) ----
  if (MODE == 1) {
    if (t < 128) {
      const float inv = 1.0f / (float)NNODES;
      float mean = stats[t] * inv;
      float var = fmaxf(stats[128 + t] * inv - mean * mean, 0.f);
      float sc = gamma[t] * rsqrtf(var + 1e-5f);
      scs[t] = sc;
      shs[t] = beta[t] - mean * sc;
    }
    __syncthreads();
  }

  // ---- build frag-ordered fp16 W in LDS directly from fp32 W (single plane) ----
#pragma unroll
  for (int oct = 0; oct < 8; ++oct) {
    int f8 = oct * 256 + t;
    int ks = f8 >> 9, cf = (f8 >> 6) & 7, lane = f8 & 63;
    int k0 = ks * 32 + ((lane >> 4) << 3);
    int n = cf * 16 + (lane & 15);
    f16x8 hi;
#pragma unroll
    for (int j = 0; j < 8; ++j) {
      float w = W[(k0 + j) * NF + n];
      if (MODE == 1) w *= scs[k0 + j];
      hi[j] = (_Float16)w;
    }
    *(f16x8*)(wl + f8 * 8) = hi;
  }

  // ---- b2' = b2 + sh @ W2 (MODE 1), 2-way k-parallel ----
  if (MODE == 1) {
    const int col = t & 127, half = t >> 7;
    float s = 0.f;
    for (int k = half * 64; k < half * 64 + 64; ++k) s += shs[k] * W[k * NF + col];
    red[0][half][col] = s;
  }
  __syncthreads();
  if (MODE == 1) {
    if (t < 128) b2sh[t] = bias[t] + red[0][0][t] + red[0][1][t];
    __syncthreads();
  }

  // ---- compute: 1 MFMA per (m,cf,ks) ----
  f32x4 acc[2][8];
#pragma unroll
  for (int m = 0; m < 2; ++m)
#pragma unroll
    for (int cf = 0; cf < 8; ++cf) acc[m][cf] = (f32x4){0.f, 0.f, 0.f, 0.f};

#pragma unroll
  for (int ks = 0; ks < 4; ++ks) {
#pragma unroll
    for (int cf = 0; cf < 8; ++cf) {
      const int fo = (((ks * 8 + cf) << 6) + l) << 3;   // half-elem offset
      f16x8 bh = *(const f16x8*)(wl + fo);
#pragma unroll
      for (int m = 0; m < 2; ++m) {
        acc[m][cf] = __builtin_amdgcn_mfma_f32_16x16x32_f16(areg[m][ks], bh, acc[m][cf], 0, 0, 0);
      }
    }
  }

  // ---- epilogue: D layout col = cf*16+(l&15), row = wrow0 + m*64 + (l>>4)*4 + r ----
  const int col16 = l & 15;
  const int rg = l >> 4;
  float bl_[8];
#pragma unroll
  for (int cf = 0; cf < 8; ++cf)
    bl_[cf] = (MODE == 0) ? bias[cf * 16 + col16] : b2sh[cf * 16 + col16];

  if (MODE == 0) {
    float cs[8], cq[8];
#pragma unroll
    for (int cf = 0; cf < 8; ++cf) { cs[cf] = 0.f; cq[cf] = 0.f; }
#pragma unroll
    for (int m = 0; m < 2; ++m)
#pragma unroll
      for (int cf = 0; cf < 8; ++cf) {
#pragma unroll
        for (int r = 0; r < 4; ++r) {
          int row = wrow0 + m * 64 + rg * 4 + r;
          if (row < NNODES) {
            float v = fmaxf(acc[m][cf][r] + bl_[cf], 0.f);
            outh[(size_t)row * NF + cf * 16 + col16] = (_Float16)v;
            cs[cf] += v;
            cq[cf] += v * v;
          }
        }
      }
#pragma unroll
    for (int cf = 0; cf < 8; ++cf) {
      cs[cf] += __shfl_xor(cs[cf], 16); cs[cf] += __shfl_xor(cs[cf], 32);
      cq[cf] += __shfl_xor(cq[cf], 16); cq[cf] += __shfl_xor(cq[cf], 32);
    }
    __syncthreads();
    if (l < 16) {
#pragma unroll
      for (int cf = 0; cf < 8; ++cf) {
        red[0][wv][cf * 16 + l] = cs[cf];
        red[1][wv][cf * 16 + l] = cq[cf];
      }
    }
    __syncthreads();
    if (t < 128) {
      float s = red[0][0][t] + red[0][1][t] + red[0][2][t] + red[0][3][t];
      float q = red[1][0][t] + red[1][1][t] + red[1][2][t] + red[1][3][t];
      unsafeAtomicAdd(stats + t, s);
      unsafeAtomicAdd(stats + 128 + t, q);
    }
  } else {
#pragma unroll
    for (int m = 0; m < 2; ++m)
#pragma unroll
      for (int cf = 0; cf < 8; ++cf) {
#pragma unroll
        for (int r = 0; r < 4; ++r) {
          int row = wrow0 + m * 64 + rg * 4 + r;
          if (row < NNODES)
            outf[(size_t)row * NF + cf * 16 + col16] = acc[m][cf][r] + bl_[cf];
        }
      }
  }
}

extern "C" void kernel_launch(void* const* d_in, const int* in_sizes, int n_in,
                              void* d_out, int out_size, void* d_ws, size_t ws_size,
                              hipStream_t stream) {
  const float* x     = (const float*)d_in[0];
  const int*   ei    = (const int*)d_in[1];
  const float* W1    = (const float*)d_in[2];
  const float* b1    = (const float*)d_in[3];
  const float* gamma = (const float*)d_in[4];
  const float* beta  = (const float*)d_in[5];
  const float* W2    = (const float*)d_in[6];
  const float* b2    = (const float*)d_in[7];
  float* out = (float*)d_out;

  // h (gather output, fp16) lives in d_out — fully consumed by GEMM1 before GEMM2
  // overwrites d_out with the final fp32 result.
  _Float16* h = (_Float16*)d_out;

  // workspace layout (~31 MB); 16B alignment maintained
  float*          stats  = (float*)d_ws;                        // [512]
  int*            cnt    = (int*)(stats + 512);                 // [P1AB*BINS] pad 61376
  int*            basep  = cnt + 61376;                         // [P1AB*BINS] pad 61376
  int*            gtot   = basep + 61376;                       // [256]
  int*            begdeg = gtot + 256;                          // [50176]
  unsigned*       binbuf = (unsigned*)(begdeg + 50176);         // [BINS*BINCAP] 3.2 MB
  unsigned short* slot   = (unsigned short*)(binbuf + BINS * BINCAP); // 1.6 MB
  unsigned short* xh     = slot + BINS * BINCAP;                // [NNODES*NF] fp16 12.8 MB
  _Float16*       h1     = (_Float16*)(xh + (size_t)NNODES * NF);     // 12.8 MB

  k_prep   <<<XB + P1AB, 256, 0, stream>>>(x, ei, xh, cnt, stats);
  k_p1b    <<<BINS, 512, 0, stream>>>(cnt, basep, gtot);
  k_p1c    <<<P1AB, 256, 0, stream>>>(ei, basep, binbuf);
  k_p2     <<<BINS, 256, 0, stream>>>(binbuf, gtot, begdeg, slot);
  k_gather <<<(NNODES + 3) / 4, 256, 0, stream>>>(xh, begdeg, slot, h);
  k_gemm<0><<<(NNODES + 127) / 128, 256, 0, stream>>>(h, W1, b1, nullptr, nullptr,
                                                      stats, h1, nullptr);
  k_gemm<1><<<(NNODES + 127) / 128, 256, 0, stream>>>(h1, W2, b2, gamma, beta,
                                                      stats, nullptr, out);
}